// Round 1
// baseline (1004.084 us; speedup 1.0000x reference)
//
#include <hip/hip_runtime.h>
#include <hip/hip_bf16.h>

#define DIM   512
#define HID   2048
#define MT    32            // tokens per block
#define KS1   16            // 512/32  k-steps GEMM1
#define KS2   64            // 2048/32 k-steps GEMM2
#define NT1   128           // 2048/16 n-tiles GEMM1
#define NT2   32            // 512/16  n-tiles GEMM2

typedef __attribute__((ext_vector_type(8))) short short8;   // MFMA A/B frag (8 bf16)
typedef __attribute__((ext_vector_type(4))) short short4v;
typedef __attribute__((ext_vector_type(4))) float f32x4;    // MFMA C/D frag

static __device__ __forceinline__ unsigned short f2bf(float f) {
  __hip_bfloat16 b = __float2bfloat16(f);   // RNE
  unsigned short s;
  __builtin_memcpy(&s, &b, 2);
  return s;
}
static __device__ __forceinline__ float bf2f(unsigned short u) {
  unsigned v = ((unsigned)u) << 16;
  float f;
  __builtin_memcpy(&f, &v, 4);
  return f;
}

// ---------------- K0a: per-block partial sums of |w| ----------------
__global__ void k_wabs(const float* __restrict__ w1, const float* __restrict__ w2,
                       float* __restrict__ part) {
  const int b = blockIdx.x;
  const float* src = (b < 256 ? w1 : w2) + (size_t)(b & 255) * 4096 + threadIdx.x * 16;
  float s = 0.f;
#pragma unroll
  for (int i = 0; i < 4; ++i) {
    float4 v = *(const float4*)(src + i * 4);
    s += fabsf(v.x) + fabsf(v.y) + fabsf(v.z) + fabsf(v.w);
  }
  __shared__ float red[256];
  red[threadIdx.x] = s;
  __syncthreads();
  for (int off = 128; off > 0; off >>= 1) {
    if (threadIdx.x < (unsigned)off) red[threadIdx.x] += red[threadIdx.x + off];
    __syncthreads();
  }
  if (threadIdx.x == 0) part[b] = red[0];
}

// ---------------- K0b: final mean-abs -> scales (deterministic) ----------------
__global__ void k_wscale(const float* __restrict__ part, float* __restrict__ scales) {
  __shared__ float s1[256], s2[256];
  s1[threadIdx.x] = part[threadIdx.x];
  s2[threadIdx.x] = part[256 + threadIdx.x];
  __syncthreads();
  for (int off = 128; off > 0; off >>= 1) {
    if (threadIdx.x < (unsigned)off) {
      s1[threadIdx.x] += s1[threadIdx.x + off];
      s2[threadIdx.x] += s2[threadIdx.x + off];
    }
    __syncthreads();
  }
  if (threadIdx.x == 0) {
    const float mc1 = fmaxf(s1[0] / 1048576.f, 1e-5f);  // clip(mean|w1|, 1e-5)
    const float mc2 = fmaxf(s2[0] / 1048576.f, 1e-5f);
    scales[0] = mc1; scales[1] = 1.f / mc1;             // multiplier, scale_w
    scales[2] = mc2; scales[3] = 1.f / mc2;
  }
}

// ---------------- K1: ternary-quantize weights, pack in MFMA fragment order ----
// packed[(nt*KS + ks)*64 + lane][8] = t( w[nt*16 + (lane&15)][ks*32 + (lane>>4)*8 + j] )
__global__ void k_pack(const float* __restrict__ w1, const float* __restrict__ w2,
                       const float* __restrict__ scales,
                       unsigned short* __restrict__ p1, unsigned short* __restrict__ p2) {
  const int b = blockIdx.x;
  const bool isw2 = b >= 512;
  const float* w = isw2 ? w2 : w1;
  const float scl = isw2 ? scales[3] : scales[1];
  unsigned short* p = isw2 ? p2 : p1;
  const int K  = isw2 ? HID : DIM;
  const int KS = isw2 ? KS2 : KS1;
  const int slot = (b & 511) * 256 + threadIdx.x;  // 0..131071
  const int lane = slot & 63;
  const int fr   = slot >> 6;                      // nt*KS + ks
  const int nt   = fr / KS;
  const int ks   = fr - nt * KS;
  const int n  = nt * 16 + (lane & 15);
  const int k0 = ks * 32 + (lane >> 4) * 8;
  const float* src = w + (size_t)n * K + k0;
  unsigned short* dst = p + (size_t)slot * 8;
#pragma unroll
  for (int j = 0; j < 8; ++j) {
    float t = fminf(fmaxf(rintf(src[j] * scl), -1.f), 1.f);  // ternary int, exact bf16
    dst[j] = f2bf(t);
  }
}

// ---------------- K2: fused quant -> GEMM1 -> GELU -> quant -> GEMM2 -> residual
__global__ __launch_bounds__(512, 2) void k_fused(
    const float* __restrict__ x, const float* __restrict__ b1,
    const float* __restrict__ b2, const unsigned short* __restrict__ p1,
    const unsigned short* __restrict__ p2, const float* __restrict__ scales,
    float* __restrict__ out) {
  // 32 KB + 128 KB = 160 KiB exactly (scratch overlays xq after GEMM1)
  __shared__ __align__(16) unsigned short xq[MT * DIM];
  __shared__ __align__(16) unsigned short hb[MT * HID];

  const int tid = threadIdx.x;
  const int wv  = tid >> 6;        // wave 0..7
  const int ln  = tid & 63;
  const int lg  = ln >> 4;         // lane group 0..3
  const int lr  = ln & 15;
  const int tok0 = blockIdx.x * MT;
  const float wsc1 = scales[0];
  const float wsc2 = scales[2];

  // ---- step 1: load x, per-token absmax int8 quant -> xq (bf16-integer, swizzled)
  {
    const int trow = tid >> 4;     // token row 0..31 (16 threads per token)
    const int j    = tid & 15;
    const float* xr = x + (size_t)(tok0 + trow) * DIM;
    float4 v[8];
    float am = 0.f;
#pragma unroll
    for (int i = 0; i < 8; ++i) {
      v[i] = *(const float4*)(xr + (i * 16 + j) * 4);
      am = fmaxf(am, fmaxf(fmaxf(fabsf(v[i].x), fabsf(v[i].y)),
                           fmaxf(fabsf(v[i].z), fabsf(v[i].w))));
    }
#pragma unroll
    for (int m = 1; m < 16; m <<= 1) am = fmaxf(am, __shfl_xor(am, m));
    const float mc  = fmaxf(am, 1e-5f);
    const float scl = 127.f / mc;
    const int   swz = (trow & 7) << 4;
#pragma unroll
    for (int i = 0; i < 8; ++i) {
      short4v q;
      q.x = (short)f2bf(fminf(fmaxf(rintf(v[i].x * scl), -128.f), 127.f));
      q.y = (short)f2bf(fminf(fmaxf(rintf(v[i].y * scl), -128.f), 127.f));
      q.z = (short)f2bf(fminf(fmaxf(rintf(v[i].z * scl), -128.f), 127.f));
      q.w = (short)f2bf(fminf(fmaxf(rintf(v[i].w * scl), -128.f), 127.f));
      const int colb = (i * 16 + j) * 8;                        // byte offset in row
      *(short4v*)&xq[trow * DIM + ((colb ^ swz) >> 1)] = q;
    }
    if (j == 0) ((float*)hb)[trow] = mc / 127.f;  // broadcast recip_x via hb (dead region)
  }
  __syncthreads();
  float rx[2][4];
#pragma unroll
  for (int mt = 0; mt < 2; ++mt)
#pragma unroll
    for (int r = 0; r < 4; ++r)
      rx[mt][r] = ((float*)hb)[mt * 16 + lg * 4 + r];
  __syncthreads();   // hb free for h from here on

  // ---- GEMM1: C[32 x 2048] = xq * w1q^T, wave owns 16 n-tiles, 2 chunks of 8
  float hmax[2][4] = {{0.f, 0.f, 0.f, 0.f}, {0.f, 0.f, 0.f, 0.f}};
#pragma unroll 1
  for (int ch = 0; ch < 2; ++ch) {
    f32x4 acc[8][2];
#pragma unroll
    for (int i = 0; i < 8; ++i) {
      acc[i][0] = (f32x4){0.f, 0.f, 0.f, 0.f};
      acc[i][1] = (f32x4){0.f, 0.f, 0.f, 0.f};
    }
    const int ntbase = wv * 16 + ch * 8;
    for (int ks = 0; ks < KS1; ++ks) {
      short8 a[2];
#pragma unroll
      for (int mt = 0; mt < 2; ++mt) {
        const int row = mt * 16 + lr;
        const int kb  = ks * 64 + lg * 16;
        a[mt] = *(const short8*)&xq[row * DIM + ((kb ^ ((row & 7) << 4)) >> 1)];
      }
#pragma unroll
      for (int ntI = 0; ntI < 8; ++ntI) {
        const int nt = ntbase + ntI;
        const short8 bfr = *(const short8*)&p1[(size_t)((nt * KS1 + ks) * 64 + ln) * 8];
        acc[ntI][0] = __builtin_amdgcn_mfma_f32_16x16x32_bf16(a[0], bfr, acc[ntI][0], 0, 0, 0);
        acc[ntI][1] = __builtin_amdgcn_mfma_f32_16x16x32_bf16(a[1], bfr, acc[ntI][1], 0, 0, 0);
      }
    }
    // epilogue: h = acc*recip_x*wsc1 + b1 ; exact GELU ; store bf16 ; track row |max|
#pragma unroll
    for (int ntI = 0; ntI < 8; ++ntI) {
      const int nt  = ntbase + ntI;
      const int col = nt * 16 + lr;
      const float bias = b1[col];
#pragma unroll
      for (int mt = 0; mt < 2; ++mt) {
#pragma unroll
        for (int r = 0; r < 4; ++r) {
          const int row = mt * 16 + lg * 4 + r;          // C/D: col=lane&15, row=(lane>>4)*4+r
          const float hv = acc[ntI][mt][r] * (rx[mt][r] * wsc1) + bias;
          const float g  = 0.5f * hv * (1.f + erff(hv * 0.70710678118654752f));
          hmax[mt][r] = fmaxf(hmax[mt][r], fabsf(g));
          hb[row * HID + (((col * 2) ^ ((row & 7) << 4)) >> 1)] = f2bf(g);
        }
      }
    }
  }
  __syncthreads();   // all GEMM1 reads of xq done -> xq becomes scratch

  float* scrP = (float*)xq;          // [8 waves][32 tok] partial row-max
  float* scrS = (float*)xq + 256;    // scale2 per token
  float* scrR = (float*)xq + 320;    // recip2 per token
#pragma unroll
  for (int m = 1; m < 16; m <<= 1)
#pragma unroll
    for (int mt = 0; mt < 2; ++mt)
#pragma unroll
      for (int r = 0; r < 4; ++r)
        hmax[mt][r] = fmaxf(hmax[mt][r], __shfl_xor(hmax[mt][r], m));
  if (lr == 0) {
#pragma unroll
    for (int mt = 0; mt < 2; ++mt)
#pragma unroll
      for (int r = 0; r < 4; ++r)
        scrP[wv * 32 + mt * 16 + lg * 4 + r] = hmax[mt][r];
  }
  __syncthreads();
  if (tid < MT) {
    float m = scrP[tid];
#pragma unroll
    for (int w = 1; w < 8; ++w) m = fmaxf(m, scrP[w * 32 + tid]);
    const float mc = fmaxf(m, 1e-5f);
    scrS[tid] = 127.f / mc;
    scrR[tid] = mc / 127.f;
  }
  __syncthreads();

  // ---- re-quantize h in place (bf16-integer values for GEMM2)
  {
    const int trow = tid >> 4;
    const int j    = tid & 15;
    const float s2 = scrS[trow];
    const int  swz = (trow & 7) << 4;
    unsigned short* rowp = hb + trow * HID;
#pragma unroll
    for (int i = 0; i < 16; ++i) {
      const int colb = i * 256 + j * 16;   // contiguous per i across j -> conflict-free
      short8* pp = (short8*)&rowp[(colb ^ swz) >> 1];
      short8 vv = *pp;
#pragma unroll
      for (int e = 0; e < 8; ++e) {
        const float f = bf2f((unsigned short)vv[e]);
        vv[e] = (short)f2bf(fminf(fmaxf(rintf(f * s2), -128.f), 127.f));
      }
      *pp = vv;
    }
  }
  __syncthreads();

  // ---- GEMM2: C[32 x 512] = hq * w2q^T, wave owns 4 n-tiles
  f32x4 acc2[4][2];
#pragma unroll
  for (int i = 0; i < 4; ++i) {
    acc2[i][0] = (f32x4){0.f, 0.f, 0.f, 0.f};
    acc2[i][1] = (f32x4){0.f, 0.f, 0.f, 0.f};
  }
  for (int ks = 0; ks < KS2; ++ks) {
    short8 a[2];
#pragma unroll
    for (int mt = 0; mt < 2; ++mt) {
      const int row = mt * 16 + lr;
      const int kb  = ks * 64 + lg * 16;
      a[mt] = *(const short8*)&hb[row * HID + ((kb ^ ((row & 7) << 4)) >> 1)];
    }
#pragma unroll
    for (int ntI = 0; ntI < 4; ++ntI) {
      const int nt = wv * 4 + ntI;
      const short8 bfr = *(const short8*)&p2[(size_t)((nt * KS2 + ks) * 64 + ln) * 8];
      acc2[ntI][0] = __builtin_amdgcn_mfma_f32_16x16x32_bf16(a[0], bfr, acc2[ntI][0], 0, 0, 0);
      acc2[ntI][1] = __builtin_amdgcn_mfma_f32_16x16x32_bf16(a[1], bfr, acc2[ntI][1], 0, 0, 0);
    }
  }
  float r2[2][4];
#pragma unroll
  for (int mt = 0; mt < 2; ++mt)
#pragma unroll
    for (int r = 0; r < 4; ++r) r2[mt][r] = scrR[mt * 16 + lg * 4 + r];
#pragma unroll
  for (int ntI = 0; ntI < 4; ++ntI) {
    const int col = (wv * 4 + ntI) * 16 + lr;
    const float bias = b2[col];
#pragma unroll
    for (int mt = 0; mt < 2; ++mt) {
#pragma unroll
      for (int r = 0; r < 4; ++r) {
        const int row = mt * 16 + lg * 4 + r;
        const size_t gidx = (size_t)(tok0 + row) * DIM + col;
        out[gidx] = acc2[ntI][mt][r] * (r2[mt][r] * wsc2) + bias + x[gidx];
      }
    }
  }
}

extern "C" void kernel_launch(void* const* d_in, const int* in_sizes, int n_in,
                              void* d_out, int out_size, void* d_ws, size_t ws_size,
                              hipStream_t stream) {
  const float* x  = (const float*)d_in[0];
  const float* w1 = (const float*)d_in[1];
  const float* b1 = (const float*)d_in[2];
  const float* w2 = (const float*)d_in[3];
  const float* b2 = (const float*)d_in[4];
  float* out = (float*)d_out;

  // ws layout: [0,2KB) partials | [2KB,+16B) scales | 4KB: p1 (2MB) | p2 (2MB)
  float* wpart   = (float*)d_ws;
  float* wscales = wpart + 512;
  unsigned short* p1 = (unsigned short*)((char*)d_ws + 4096);
  unsigned short* p2 = (unsigned short*)((char*)d_ws + 4096 + 2097152);

  k_wabs<<<512, 256, 0, stream>>>(w1, w2, wpart);
  k_wscale<<<1, 256, 0, stream>>>(wpart, wscales);
  k_pack<<<1024, 256, 0, stream>>>(w1, w2, wscales, p1, p2);
  k_fused<<<2048, 512, 0, stream>>>(x, b1, b2, p1, p2, wscales, out);
}

// Round 2
// 796.321 us; speedup vs baseline: 1.2609x; 1.2609x over previous
//
#include <hip/hip_runtime.h>
#include <hip/hip_bf16.h>

#define DIM 512
#define HID 2048
#define MT  32
#define KS1 8     // 512/64  k-steps GEMM1 (i8 K=64)
#define KS2 32    // 2048/64 k-steps GEMM2

typedef __attribute__((ext_vector_type(4))) int   i32x4;   // i8 MFMA A/B (16 bytes) and C/D (4 i32)

static __device__ __forceinline__ unsigned short f2bf(float f) {
  __hip_bfloat16 b = __float2bfloat16(f);   // RNE
  unsigned short s;
  __builtin_memcpy(&s, &b, 2);
  return s;
}
static __device__ __forceinline__ float bf2f(unsigned short u) {
  unsigned v = ((unsigned)u) << 16;
  float f;
  __builtin_memcpy(&f, &v, 4);
  return f;
}

// ---------------- K0a: per-block partial sums of |w| ----------------
__global__ void k_wabs(const float* __restrict__ w1, const float* __restrict__ w2,
                       float* __restrict__ part) {
  const int b = blockIdx.x;
  const float* src = (b < 256 ? w1 : w2) + (size_t)(b & 255) * 4096 + threadIdx.x * 16;
  float s = 0.f;
#pragma unroll
  for (int i = 0; i < 4; ++i) {
    float4 v = *(const float4*)(src + i * 4);
    s += fabsf(v.x) + fabsf(v.y) + fabsf(v.z) + fabsf(v.w);
  }
  __shared__ float red[256];
  red[threadIdx.x] = s;
  __syncthreads();
  for (int off = 128; off > 0; off >>= 1) {
    if (threadIdx.x < (unsigned)off) red[threadIdx.x] += red[threadIdx.x + off];
    __syncthreads();
  }
  if (threadIdx.x == 0) part[b] = red[0];
}

// ---------------- K0b: final mean-abs -> scales ----------------
__global__ void k_wscale(const float* __restrict__ part, float* __restrict__ scales) {
  __shared__ float s1[256], s2[256];
  s1[threadIdx.x] = part[threadIdx.x];
  s2[threadIdx.x] = part[256 + threadIdx.x];
  __syncthreads();
  for (int off = 128; off > 0; off >>= 1) {
    if (threadIdx.x < (unsigned)off) {
      s1[threadIdx.x] += s1[threadIdx.x + off];
      s2[threadIdx.x] += s2[threadIdx.x + off];
    }
    __syncthreads();
  }
  if (threadIdx.x == 0) {
    const float mc1 = fmaxf(s1[0] / 1048576.f, 1e-5f);
    const float mc2 = fmaxf(s2[0] / 1048576.f, 1e-5f);
    scales[0] = mc1; scales[1] = 1.f / mc1;
    scales[2] = mc2; scales[3] = 1.f / mc2;
  }
}

// ---------------- K1: ternary-quantize weights, pack i8 MFMA fragments ----
// frag (nt,ks): lane l holds w[nt*16+(l&15)][ks*64+(l>>4)*16 + j], j=0..15 (16 bytes)
__global__ void k_pack(const float* __restrict__ w1, const float* __restrict__ w2,
                       const float* __restrict__ scales,
                       signed char* __restrict__ p1, signed char* __restrict__ p2) {
  int slot = blockIdx.x * 256 + threadIdx.x;    // 0..131071 (first 65536 -> p1)
  const bool isw2 = slot >= 65536;
  const float* w = isw2 ? w2 : w1;
  const float scl = isw2 ? scales[3] : scales[1];
  signed char* p = isw2 ? p2 : p1;
  const int K  = isw2 ? HID : DIM;
  const int KS = isw2 ? KS2 : KS1;
  slot &= 65535;
  const int lane = slot & 63;
  const int fr   = slot >> 6;
  const int nt   = fr / KS;
  const int ks   = fr - nt * KS;
  const int n  = nt * 16 + (lane & 15);
  const int k0 = ks * 64 + (lane >> 4) * 16;
  const float* src = w + (size_t)n * K + k0;
  i32x4 outv;
#pragma unroll
  for (int d = 0; d < 4; ++d) {
    unsigned v = 0;
#pragma unroll
    for (int e = 0; e < 4; ++e) {
      int q = (int)fminf(fmaxf(rintf(src[d * 4 + e] * scl), -1.f), 1.f);
      v |= ((unsigned)(q & 255)) << (8 * e);
    }
    outv[d] = (int)v;
  }
  *(i32x4*)(p + (size_t)slot * 16) = outv;
}

// ---------------- K2: fused quant -> GEMM1(i8) -> GELU -> quant -> GEMM2(i8) -> residual
__global__ __launch_bounds__(512, 2) void k_fused(
    const float* __restrict__ x, const float* __restrict__ b1,
    const float* __restrict__ b2, const signed char* __restrict__ p1,
    const signed char* __restrict__ p2, const float* __restrict__ scales,
    float* __restrict__ out) {
  __shared__ __align__(16) signed char qh[MT * HID];  // 64 KB; [0,16K) doubles as xq
  __shared__ float scrP[8 * MT];                      // rx broadcast, then hmax partials
  __shared__ float scrS[MT], scrR[MT];

  signed char* xq = qh;   // 32 x 512 i8, dead before qh written

  const int tid = threadIdx.x;
  const int wv = tid >> 6, ln = tid & 63, lg = ln >> 4, lr = ln & 15;
  const int tok0 = blockIdx.x * MT;
  const float wsc1 = scales[0], wsc2 = scales[2];

  // ---- phase 1: load x, per-token absmax int8 quant -> xq (swizzled)
  {
    const int trow = tid >> 4, j = tid & 15;
    const float* xr = x + (size_t)(tok0 + trow) * DIM;
    float4 v[8];
    float am = 0.f;
#pragma unroll
    for (int i = 0; i < 8; ++i) {
      v[i] = ((const float4*)xr)[i * 16 + j];
      am = fmaxf(am, fmaxf(fmaxf(fabsf(v[i].x), fabsf(v[i].y)),
                           fmaxf(fabsf(v[i].z), fabsf(v[i].w))));
    }
#pragma unroll
    for (int m = 1; m < 16; m <<= 1) am = fmaxf(am, __shfl_xor(am, m));
    const float mc  = fmaxf(am, 1e-5f);
    const float scl = 127.f / mc;
    const int swz = (trow & 7) << 4;
#pragma unroll
    for (int i = 0; i < 8; ++i) {
      int q0 = (int)fminf(fmaxf(rintf(v[i].x * scl), -128.f), 127.f);
      int q1 = (int)fminf(fmaxf(rintf(v[i].y * scl), -128.f), 127.f);
      int q2 = (int)fminf(fmaxf(rintf(v[i].z * scl), -128.f), 127.f);
      int q3 = (int)fminf(fmaxf(rintf(v[i].w * scl), -128.f), 127.f);
      unsigned u = (unsigned)(q0 & 255) | ((unsigned)(q1 & 255) << 8) |
                   ((unsigned)(q2 & 255) << 16) | ((unsigned)(q3 & 255) << 24);
      *(unsigned*)&xq[trow * 512 + ((i * 64 + j * 4) ^ swz)] = u;
    }
    if (j == 0) scrP[trow] = mc * (1.f / 127.f);
  }
  __syncthreads();
  float rx[2][4];
#pragma unroll
  for (int mt = 0; mt < 2; ++mt)
#pragma unroll
    for (int r = 0; r < 4; ++r) rx[mt][r] = scrP[mt * 16 + lg * 4 + r];

  // ---- GEMM1: [32 x 2048] i8, wave owns 16 n-tiles in 2 chunks; g kept in regs (bf16)
  unsigned gpack[2][8][2][2];
  float hmax[2][4] = {{0.f, 0.f, 0.f, 0.f}, {0.f, 0.f, 0.f, 0.f}};
#pragma unroll
  for (int ch = 0; ch < 2; ++ch) {
    i32x4 acc[8][2];
#pragma unroll
    for (int t = 0; t < 8; ++t) {
      acc[t][0] = (i32x4){0, 0, 0, 0};
      acc[t][1] = (i32x4){0, 0, 0, 0};
    }
    const int ntbase = wv * 16 + ch * 8;
    const signed char* bp = p1 + ((size_t)(ntbase * KS1) * 64 + ln) * 16;
    i32x4 bA[8], bB[8];
#pragma unroll
    for (int t = 0; t < 8; ++t) bA[t] = *(const i32x4*)(bp + (size_t)t * (KS1 * 1024));
#pragma unroll
    for (int ks = 0; ks < KS1; ++ks) {
      if (ks + 1 < KS1) {
#pragma unroll
        for (int t = 0; t < 8; ++t)
          ((ks & 1) ? bA : bB)[t] =
              *(const i32x4*)(bp + (size_t)(ks + 1) * 1024 + (size_t)t * (KS1 * 1024));
      }
      i32x4 a[2];
#pragma unroll
      for (int mt = 0; mt < 2; ++mt) {
        const int row = mt * 16 + lr;
        a[mt] = *(const i32x4*)&xq[row * 512 + ((ks * 64 + lg * 16) ^ ((row & 7) << 4))];
      }
#pragma unroll
      for (int t = 0; t < 8; ++t) {
        i32x4 bf = (ks & 1) ? bB[t] : bA[t];
        acc[t][0] = __builtin_amdgcn_mfma_i32_16x16x64_i8(a[0], bf, acc[t][0], 0, 0, 0);
        acc[t][1] = __builtin_amdgcn_mfma_i32_16x16x64_i8(a[1], bf, acc[t][1], 0, 0, 0);
      }
    }
    // epilogue: h = acc*rx*wsc1 + b1 ; exact GELU ; pack bf16 into regs ; track |max|
#pragma unroll
    for (int t = 0; t < 8; ++t) {
      const int col = (ntbase + t) * 16 + lr;
      const float bias = b1[col];
#pragma unroll
      for (int mt = 0; mt < 2; ++mt) {
#pragma unroll
        for (int pr = 0; pr < 2; ++pr) {
          unsigned v = 0;
#pragma unroll
          for (int hf = 0; hf < 2; ++hf) {
            const int r = pr * 2 + hf;
            const float hv = (float)acc[t][mt][r] * (rx[mt][r] * wsc1) + bias;
            const float g  = 0.5f * hv * (1.f + erff(hv * 0.70710678118654752f));
            hmax[mt][r] = fmaxf(hmax[mt][r], fabsf(g));
            v |= ((unsigned)f2bf(g)) << (16 * hf);
          }
          gpack[ch][t][mt][pr] = v;
        }
      }
    }
  }
  __syncthreads();   // xq reads + scrP(rx) reads complete -> both reusable

  // ---- per-token max across waves
#pragma unroll
  for (int m = 1; m < 16; m <<= 1)
#pragma unroll
    for (int mt = 0; mt < 2; ++mt)
#pragma unroll
      for (int r = 0; r < 4; ++r)
        hmax[mt][r] = fmaxf(hmax[mt][r], __shfl_xor(hmax[mt][r], m));
  if (lr == 0) {
#pragma unroll
    for (int mt = 0; mt < 2; ++mt)
#pragma unroll
      for (int r = 0; r < 4; ++r)
        scrP[wv * 32 + mt * 16 + lg * 4 + r] = hmax[mt][r];
  }
  __syncthreads();
  if (tid < MT) {
    float m = scrP[tid];
#pragma unroll
    for (int w = 1; w < 8; ++w) m = fmaxf(m, scrP[w * 32 + tid]);
    const float mc = fmaxf(m, 1e-5f);
    scrS[tid] = 127.f / mc;
    scrR[tid] = mc * (1.f / 127.f);
  }
  __syncthreads();

  // ---- quantize g (from regs) -> qh i8 (swizzled), overlays xq
  {
    float s2[2][4];
#pragma unroll
    for (int mt = 0; mt < 2; ++mt)
#pragma unroll
      for (int r = 0; r < 4; ++r) s2[mt][r] = scrS[mt * 16 + lg * 4 + r];
#pragma unroll
    for (int ch = 0; ch < 2; ++ch)
#pragma unroll
      for (int t = 0; t < 8; ++t) {
        const int col = wv * 256 + ch * 128 + t * 16 + lr;
#pragma unroll
        for (int mt = 0; mt < 2; ++mt)
#pragma unroll
          for (int pr = 0; pr < 2; ++pr) {
            const unsigned v = gpack[ch][t][mt][pr];
#pragma unroll
            for (int hf = 0; hf < 2; ++hf) {
              const int r = pr * 2 + hf;
              const int row = mt * 16 + lg * 4 + r;
              const float g = bf2f((unsigned short)(hf ? (v >> 16) : (v & 0xffff)));
              const int q = (int)fminf(fmaxf(rintf(g * s2[mt][r]), -128.f), 127.f);
              qh[row * 2048 + (col ^ ((row & 7) << 4))] = (signed char)q;
            }
          }
      }
  }
  __syncthreads();

  // ---- GEMM2: [32 x 512] i8, wave owns 4 n-tiles
  i32x4 acc2[4][2];
#pragma unroll
  for (int t = 0; t < 4; ++t) {
    acc2[t][0] = (i32x4){0, 0, 0, 0};
    acc2[t][1] = (i32x4){0, 0, 0, 0};
  }
  const signed char* bp2 = p2 + ((size_t)(wv * 4 * KS2) * 64 + ln) * 16;
  i32x4 cA[4], cB[4];
#pragma unroll
  for (int t = 0; t < 4; ++t) cA[t] = *(const i32x4*)(bp2 + (size_t)t * (KS2 * 1024));
#pragma unroll
  for (int ks = 0; ks < KS2; ++ks) {
    if (ks + 1 < KS2) {
#pragma unroll
      for (int t = 0; t < 4; ++t)
        ((ks & 1) ? cA : cB)[t] =
            *(const i32x4*)(bp2 + (size_t)(ks + 1) * 1024 + (size_t)t * (KS2 * 1024));
    }
    i32x4 a[2];
#pragma unroll
    for (int mt = 0; mt < 2; ++mt) {
      const int row = mt * 16 + lr;
      a[mt] = *(const i32x4*)&qh[row * 2048 + ((ks * 64 + lg * 16) ^ ((row & 7) << 4))];
    }
#pragma unroll
    for (int t = 0; t < 4; ++t) {
      i32x4 bf = (ks & 1) ? cB[t] : cA[t];
      acc2[t][0] = __builtin_amdgcn_mfma_i32_16x16x64_i8(a[0], bf, acc2[t][0], 0, 0, 0);
      acc2[t][1] = __builtin_amdgcn_mfma_i32_16x16x64_i8(a[1], bf, acc2[t][1], 0, 0, 0);
    }
  }
  float r2[2][4];
#pragma unroll
  for (int mt = 0; mt < 2; ++mt)
#pragma unroll
    for (int r = 0; r < 4; ++r) r2[mt][r] = scrR[mt * 16 + lg * 4 + r];
#pragma unroll
  for (int t = 0; t < 4; ++t) {
    const int col = (wv * 4 + t) * 16 + lr;
    const float bias = b2[col];
#pragma unroll
    for (int mt = 0; mt < 2; ++mt) {
#pragma unroll
      for (int r = 0; r < 4; ++r) {
        const int row = mt * 16 + lg * 4 + r;
        const size_t gidx = (size_t)(tok0 + row) * DIM + col;
        out[gidx] = (float)acc2[t][mt][r] * (r2[mt][r] * wsc2) + bias + x[gidx];
      }
    }
  }
}

extern "C" void kernel_launch(void* const* d_in, const int* in_sizes, int n_in,
                              void* d_out, int out_size, void* d_ws, size_t ws_size,
                              hipStream_t stream) {
  const float* x  = (const float*)d_in[0];
  const float* w1 = (const float*)d_in[1];
  const float* b1 = (const float*)d_in[2];
  const float* w2 = (const float*)d_in[3];
  const float* b2 = (const float*)d_in[4];
  float* out = (float*)d_out;

  // ws layout: [0,2KB) partials | scales | 4KB: p1 (1MB) | p2 (1MB)
  float* wpart   = (float*)d_ws;
  float* wscales = wpart + 512;
  signed char* p1 = (signed char*)((char*)d_ws + 4096);
  signed char* p2 = (signed char*)((char*)d_ws + 4096 + 1048576);

  k_wabs<<<512, 256, 0, stream>>>(w1, w2, wpart);
  k_wscale<<<1, 256, 0, stream>>>(wpart, wscales);
  k_pack<<<512, 256, 0, stream>>>(w1, w2, wscales, p1, p2);
  k_fused<<<2048, 512, 0, stream>>>(x, b1, b2, p1, p2, wscales, out);
}